// Round 7
// baseline (66.240 us; speedup 1.0000x reference)
//
#include <hip/hip_runtime.h>
#include <hip/hip_bf16.h>
#include <stdint.h>

#define HS 4096
#define NE 64

using half8 = __attribute__((ext_vector_type(8))) _Float16;
using f32x4 = __attribute__((ext_vector_type(4))) float;

constexpr int M_BLK = 32;            // tokens per block
constexpr int KCH   = 256;           // k per staged chunk (shared by all waves)
constexpr int NCH   = HS / KCH;      // 16 chunks
constexpr int NSLOT = (KCH / 8) * 2 * NE;   // 4096 half8 per chunk buffer

constexpr float XS  = 16.f;          // x scale (keeps xl out of f16 denormals)
constexpr float WSC = 1024.f;        // W scale (keeps Wl out of f16 denormals)
constexpr float INV_SCALE = 1.f / (XS * WSC);   // 2^-14

// Fully fused router: GEMM (split-f16 MFMA, K split across 8 waves) +
// in-block reduce + softmax + top-2. Grid = n_tokens/32 blocks of 512.
__global__ __launch_bounds__(512, 1)
void router_fused(const float* __restrict__ x, const float* __restrict__ W,
                  float* __restrict__ out, int n_tokens)
{
    __shared__ half8 wbuf[2][NSLOT];                 // 2 x 64 KiB, double buffer
    float* plds = reinterpret_cast<float*>(&wbuf[0][0]);  // epilogue partials

    const int tid = threadIdx.x;
    const int l   = tid & 63;
    const int wv  = __builtin_amdgcn_readfirstlane(tid >> 6);
    const int g   = l >> 4;              // k-group 0..3 within wave's 32-k window
    const int e   = l & 15;              // row/col within 16x16 tile
    const int m0  = blockIdx.x * M_BLK;

    // W staging mapping: thread -> (expert row, 32-float col group)
    const int we = tid >> 3;             // 0..63
    const int wc = tid & 7;              // 0..7

    // x row pointers; chunk c col base = c*KCH + wv*32 + g*8
    const float* xr0 = x + (size_t)(m0 + e) * HS + wv * 32 + g * 8;
    const float* xr1 = xr0 + (size_t)16 * HS;

    f32x4 acc[2][4];
    #pragma unroll
    for (int i = 0; i < 2; ++i)
        #pragma unroll
        for (int j = 0; j < 4; ++j) acc[i][j] = (f32x4){0.f, 0.f, 0.f, 0.f};

    // ---- prologue: x chunks 0,1 into regs; W chunk 0 into wbuf[0] ----
    float4 xc00 = *(const float4*)(xr0);
    float4 xc01 = *(const float4*)(xr0 + 4);
    float4 xc10 = *(const float4*)(xr1);
    float4 xc11 = *(const float4*)(xr1 + 4);
    float4 xn00 = *(const float4*)(xr0 + KCH);
    float4 xn01 = *(const float4*)(xr0 + KCH + 4);
    float4 xn10 = *(const float4*)(xr1 + KCH);
    float4 xn11 = *(const float4*)(xr1 + KCH + 4);

    {
        const float* wp = W + (size_t)we * HS + wc * 32;
        float4 wr0 = *(const float4*)(wp +  0), wr1 = *(const float4*)(wp +  4);
        float4 wr2 = *(const float4*)(wp +  8), wr3 = *(const float4*)(wp + 12);
        float4 wr4 = *(const float4*)(wp + 16), wr5 = *(const float4*)(wp + 20);
        float4 wr6 = *(const float4*)(wp + 24), wr7 = *(const float4*)(wp + 28);
        float4 wq[8] = {wr0, wr1, wr2, wr3, wr4, wr5, wr6, wr7};
        #pragma unroll
        for (int kq = 0; kq < 4; ++kq) {
            float f[8] = {wq[2*kq].x, wq[2*kq].y, wq[2*kq].z, wq[2*kq].w,
                          wq[2*kq+1].x, wq[2*kq+1].y, wq[2*kq+1].z, wq[2*kq+1].w};
            half8 h, lo;
            #pragma unroll
            for (int i = 0; i < 8; ++i) {
                float s = f[i] * WSC;
                _Float16 hh = (_Float16)s;
                h[i] = hh; lo[i] = (_Float16)(s - (float)hh);
            }
            const int kgl = wc * 4 + kq;
            wbuf[0][(kgl * 2 + 0) * NE + we] = h;
            wbuf[0][(kgl * 2 + 1) * NE + we] = lo;
        }
    }

    // ---- main loop: 1 lgkm-only barrier per chunk (vmcnt pipeline survives) ----
    #pragma unroll 1
    for (int c = 0; c < NCH; ++c) {
        const int cur = c & 1;
        asm volatile("s_waitcnt lgkmcnt(0)\n\ts_barrier" ::: "memory");

        // issue W raw loads for chunk c+1 (L2-resident; lands during compute)
        float4 w0, w1, w2, w3, w4, w5, w6, w7;
        if (c + 1 < NCH) {
            const float* wp = W + (size_t)we * HS + (c + 1) * KCH + wc * 32;
            w0 = *(const float4*)(wp +  0); w1 = *(const float4*)(wp +  4);
            w2 = *(const float4*)(wp +  8); w3 = *(const float4*)(wp + 12);
            w4 = *(const float4*)(wp + 16); w5 = *(const float4*)(wp + 20);
            w6 = *(const float4*)(wp + 24); w7 = *(const float4*)(wp + 28);
        }

        // rotate x pipeline; issue chunk c+2 loads (HBM, 2-chunk depth)
        float4 a00 = xc00, a01 = xc01, a10 = xc10, a11 = xc11;
        xc00 = xn00; xc01 = xn01; xc10 = xn10; xc11 = xn11;
        if (c + 2 < NCH) {
            const int off = (c + 2) * KCH;
            xn00 = *(const float4*)(xr0 + off);
            xn01 = *(const float4*)(xr0 + off + 4);
            xn10 = *(const float4*)(xr1 + off);
            xn11 = *(const float4*)(xr1 + off + 4);
        }

        // B fragments for this wave's k-window (kgl = wv*4 + g)
        const int kb = (wv * 4 + g) * 2;
        half8 bh0 = wbuf[cur][(kb + 0) * NE +  0 + e];
        half8 bl0 = wbuf[cur][(kb + 1) * NE +  0 + e];
        half8 bh1 = wbuf[cur][(kb + 0) * NE + 16 + e];
        half8 bl1 = wbuf[cur][(kb + 1) * NE + 16 + e];
        half8 bh2 = wbuf[cur][(kb + 0) * NE + 32 + e];
        half8 bl2 = wbuf[cur][(kb + 1) * NE + 32 + e];
        half8 bh3 = wbuf[cur][(kb + 0) * NE + 48 + e];
        half8 bl3 = wbuf[cur][(kb + 1) * NE + 48 + e];

        // A fragments: fp32 -> scaled f16 hi/lo
        half8 ah0, al0, ah1, al1;
        {
            float f0[8] = {a00.x, a00.y, a00.z, a00.w, a01.x, a01.y, a01.z, a01.w};
            float f1[8] = {a10.x, a10.y, a10.z, a10.w, a11.x, a11.y, a11.z, a11.w};
            #pragma unroll
            for (int i = 0; i < 8; ++i) {
                float s0 = f0[i] * XS; _Float16 h0 = (_Float16)s0;
                ah0[i] = h0; al0[i] = (_Float16)(s0 - (float)h0);
                float s1 = f1[i] * XS; _Float16 h1 = (_Float16)s1;
                ah1[i] = h1; al1[i] = (_Float16)(s1 - (float)h1);
            }
        }

        // 3-term split-f16 accumulation: xh*Wh + xl*Wh + xh*Wl
        acc[0][0] = __builtin_amdgcn_mfma_f32_16x16x32_f16(ah0, bh0, acc[0][0], 0, 0, 0);
        acc[0][0] = __builtin_amdgcn_mfma_f32_16x16x32_f16(al0, bh0, acc[0][0], 0, 0, 0);
        acc[0][0] = __builtin_amdgcn_mfma_f32_16x16x32_f16(ah0, bl0, acc[0][0], 0, 0, 0);
        acc[0][1] = __builtin_amdgcn_mfma_f32_16x16x32_f16(ah0, bh1, acc[0][1], 0, 0, 0);
        acc[0][1] = __builtin_amdgcn_mfma_f32_16x16x32_f16(al0, bh1, acc[0][1], 0, 0, 0);
        acc[0][1] = __builtin_amdgcn_mfma_f32_16x16x32_f16(ah0, bl1, acc[0][1], 0, 0, 0);
        acc[0][2] = __builtin_amdgcn_mfma_f32_16x16x32_f16(ah0, bh2, acc[0][2], 0, 0, 0);
        acc[0][2] = __builtin_amdgcn_mfma_f32_16x16x32_f16(al0, bh2, acc[0][2], 0, 0, 0);
        acc[0][2] = __builtin_amdgcn_mfma_f32_16x16x32_f16(ah0, bl2, acc[0][2], 0, 0, 0);
        acc[0][3] = __builtin_amdgcn_mfma_f32_16x16x32_f16(ah0, bh3, acc[0][3], 0, 0, 0);
        acc[0][3] = __builtin_amdgcn_mfma_f32_16x16x32_f16(al0, bh3, acc[0][3], 0, 0, 0);
        acc[0][3] = __builtin_amdgcn_mfma_f32_16x16x32_f16(ah0, bl3, acc[0][3], 0, 0, 0);
        acc[1][0] = __builtin_amdgcn_mfma_f32_16x16x32_f16(ah1, bh0, acc[1][0], 0, 0, 0);
        acc[1][0] = __builtin_amdgcn_mfma_f32_16x16x32_f16(al1, bh0, acc[1][0], 0, 0, 0);
        acc[1][0] = __builtin_amdgcn_mfma_f32_16x16x32_f16(ah1, bl0, acc[1][0], 0, 0, 0);
        acc[1][1] = __builtin_amdgcn_mfma_f32_16x16x32_f16(ah1, bh1, acc[1][1], 0, 0, 0);
        acc[1][1] = __builtin_amdgcn_mfma_f32_16x16x32_f16(al1, bh1, acc[1][1], 0, 0, 0);
        acc[1][1] = __builtin_amdgcn_mfma_f32_16x16x32_f16(ah1, bl1, acc[1][1], 0, 0, 0);
        acc[1][2] = __builtin_amdgcn_mfma_f32_16x16x32_f16(ah1, bh2, acc[1][2], 0, 0, 0);
        acc[1][2] = __builtin_amdgcn_mfma_f32_16x16x32_f16(al1, bh2, acc[1][2], 0, 0, 0);
        acc[1][2] = __builtin_amdgcn_mfma_f32_16x16x32_f16(ah1, bl2, acc[1][2], 0, 0, 0);
        acc[1][3] = __builtin_amdgcn_mfma_f32_16x16x32_f16(ah1, bh3, acc[1][3], 0, 0, 0);
        acc[1][3] = __builtin_amdgcn_mfma_f32_16x16x32_f16(al1, bh3, acc[1][3], 0, 0, 0);
        acc[1][3] = __builtin_amdgcn_mfma_f32_16x16x32_f16(ah1, bl3, acc[1][3], 0, 0, 0);

        // stage chunk c+1 into the other buffer (readers of it barriered above)
        if (c + 1 < NCH) {
            float4 wq[8] = {w0, w1, w2, w3, w4, w5, w6, w7};
            #pragma unroll
            for (int kq = 0; kq < 4; ++kq) {
                float f[8] = {wq[2*kq].x, wq[2*kq].y, wq[2*kq].z, wq[2*kq].w,
                              wq[2*kq+1].x, wq[2*kq+1].y, wq[2*kq+1].z, wq[2*kq+1].w};
                half8 h, lo;
                #pragma unroll
                for (int i = 0; i < 8; ++i) {
                    float s = f[i] * WSC;
                    _Float16 hh = (_Float16)s;
                    h[i] = hh; lo[i] = (_Float16)(s - (float)hh);
                }
                const int kgl = wc * 4 + kq;
                wbuf[cur ^ 1][(kgl * 2 + 0) * NE + we] = h;
                wbuf[cur ^ 1][(kgl * 2 + 1) * NE + we] = lo;
            }
        }
    }

    // ---- epilogue: in-block reduce over 8 K-slices + softmax + top-2 ----
    __syncthreads();                       // all waves done with wbuf reads
    #pragma unroll
    for (int mt = 0; mt < 2; ++mt)
        #pragma unroll
        for (int nt = 0; nt < 4; ++nt)
            #pragma unroll
            for (int r = 0; r < 4; ++r) {
                const int tloc = mt * 16 + g * 4 + r;
                const int ef   = nt * 16 + e;
                plds[wv * 2176 + tloc * 68 + ef] = acc[mt][nt][r];  // stride 68: 2-way banks
            }
    __syncthreads();

    #pragma unroll 1
    for (int jj = 0; jj < 4; ++jj) {       // wave wv owns tokens wv*4 .. wv*4+3
        const int tloc = wv * 4 + jj;
        float v = 0.f;
        #pragma unroll
        for (int s = 0; s < 8; ++s)
            v += plds[s * 2176 + tloc * 68 + l];
        v *= INV_SCALE;

        float m1 = v;
        #pragma unroll
        for (int off = 32; off >= 1; off >>= 1) m1 = fmaxf(m1, __shfl_xor(m1, off));
        unsigned long long b1 = __ballot(v == m1);    // lowest-index tie-break
        int i1 = __ffsll(b1) - 1;

        const float NINF = __int_as_float(0xff800000);
        float vx = (l == i1) ? NINF : v;
        float m2 = vx;
        #pragma unroll
        for (int off = 32; off >= 1; off >>= 1) m2 = fmaxf(m2, __shfl_xor(m2, off));
        unsigned long long b2 = __ballot(vx == m2);
        int i2 = __ffsll(b2) - 1;

        float s = __expf(v - m1);
        #pragma unroll
        for (int off = 32; off >= 1; off >>= 1) s += __shfl_xor(s, off);

        if (l == 0) {
            const int tok = m0 + tloc;
            float inv = 1.0f / s;
            out[(size_t)tok * 2 + 0] = inv;
            out[(size_t)tok * 2 + 1] = __expf(m2 - m1) * inv;
            out[(size_t)n_tokens * 2 + (size_t)tok * 2 + 0] = (float)i1;
            out[(size_t)n_tokens * 2 + (size_t)tok * 2 + 1] = (float)i2;
        }
    }
}

extern "C" void kernel_launch(void* const* d_in, const int* in_sizes, int n_in,
                              void* d_out, int out_size, void* d_ws, size_t ws_size,
                              hipStream_t stream)
{
    const float* x = (const float*)d_in[0];
    const float* W = (const float*)d_in[1];
    float* out = (float*)d_out;

    const int n_tokens = in_sizes[0] / HS;            // 8192
    dim3 grid(n_tokens / M_BLK);                      // 256 blocks, 1/CU
    router_fused<<<grid, 512, 0, stream>>>(x, W, out, n_tokens);
}